// Round 4
// baseline (224.631 us; speedup 1.0000x reference)
//
#include <hip/hip_runtime.h>

#define DIM       128
#define BATCH     16384
#define RELN      500
#define ALPHA     0.001f
#define CHUNK     16
#define MAXCHUNKS (BATCH / CHUNK + RELN)   // 1524 upper bound on total chunks

__device__ __forceinline__ float dot4(float4 a, float4 b) {
    return a.x * b.x + a.y * b.y + a.z * b.z + a.w * b.w;
}

// ---------- prep: ONE block does hist + scan + scatter + chunk list ----------
__global__ void __launch_bounds__(1024) prep_kernel(
    const int* __restrict__ r_idx,
    int*  __restrict__ offsets,      // [RELN+1]
    int*  __restrict__ bucket,       // [BATCH]
    int2* __restrict__ chunk_desc,   // [MAXCHUNKS] (rel, start)
    int*  __restrict__ n_chunks)
{
    __shared__ int cnt[512];
    __shared__ int offs[512];
    __shared__ int cur[512];
    const int tid = threadIdx.x;

    if (tid < 512) cnt[tid] = 0;
    __syncthreads();

    int myr[16];
    #pragma unroll
    for (int k = 0; k < 16; ++k) {
        myr[k] = r_idx[tid + k * 1024];
        atomicAdd(&cnt[myr[k]], 1);
    }
    __syncthreads();

    // inclusive scan of cnt -> offs
    if (tid < 512) offs[tid] = cnt[tid];
    __syncthreads();
    for (int d = 1; d < 512; d <<= 1) {
        int x = 0;
        if (tid < 512 && tid >= d) x = offs[tid - d];
        __syncthreads();
        if (tid < 512) offs[tid] += x;
        __syncthreads();
    }
    int excl = 0;
    if (tid < 512) {
        excl = offs[tid] - cnt[tid];
        cur[tid] = excl;
        if (tid < RELN) offsets[tid] = excl;
        if (tid == RELN - 1) offsets[RELN] = offs[tid];
    }
    __syncthreads();

    // scatter (order within a relation nondeterministic; no output depends on it)
    #pragma unroll
    for (int k = 0; k < 16; ++k) {
        const int pos = atomicAdd(&cur[myr[k]], 1);
        bucket[pos] = tid + k * 1024;
    }

    // chunk list: second scan over ceil(cnt/CHUNK)
    const int nc = (tid < RELN) ? (cnt[tid] + CHUNK - 1) / CHUNK : 0;
    __syncthreads();
    if (tid < 512) offs[tid] = nc;
    __syncthreads();
    for (int d = 1; d < 512; d <<= 1) {
        int x = 0;
        if (tid < 512 && tid >= d) x = offs[tid - d];
        __syncthreads();
        if (tid < 512) offs[tid] += x;
        __syncthreads();
    }
    if (tid == 511) n_chunks[0] = offs[511];
    if (tid < RELN) {
        const int cbase = offs[tid] - nc;
        for (int i = 0; i < nc; ++i)
            chunk_desc[cbase + i] = make_int2(tid, excl + i * CHUNK);
    }
}

// ---------- main: one block per chunk; R in regs (two sequential halves) ----------
// Wave w, lane l: hi=l>>5, c4=l&31. Thread owns 16 CONSECUTIVE rows
// rbase=32w+16hi .. +15, float4 cols [4*c4, +4). R loaded as 8 float4 (half),
// processed over all 16 elements, then the other half reusing the same regs
// (peak ~90 VGPR -> no spill/remat at the 128 cap). h applied via broadcast
// float4 LDS reads. All reduction trees slot-invariant -> deterministic.
__global__ void __launch_bounds__(256, 4) rescal_main_kernel(
    const int2*  __restrict__ chunk_desc,
    const int*   __restrict__ n_chunks,
    const int*   __restrict__ offsets,
    const int*   __restrict__ bucket,
    const int*   __restrict__ h_idx,
    const int*   __restrict__ t_idx,
    const float* __restrict__ labels,
    const float* __restrict__ ent_w,
    const float* __restrict__ rel_w,
    float*       __restrict__ scores_out,   // d_out + 1
    float2*      __restrict__ partials,     // [BATCH] (err, h2+t2)
    float*       __restrict__ chunk_r2)     // [MAXCHUNKS] e_cnt * ||R||^2
{
    // bijective XCD swizzle for nwg = MAXCHUNKS = 1524: q=190, r=4
    const int bid  = blockIdx.x;
    const int xcd  = bid & 7;
    const int j    = bid >> 3;
    const int q    = MAXCHUNKS / 8;          // 190
    const int rr_  = MAXCHUNKS % 8;          // 4
    const int cid  = (xcd < rr_ ? xcd * (q + 1) : rr_ * (q + 1) + (xcd - rr_) * q) + j;

    const int total = n_chunks[0];
    if (cid >= total) return;

    const int tid = threadIdx.x;
    const int w   = tid >> 6;
    const int l   = tid & 63;
    const int hi  = l >> 5;
    const int c4  = l & 31;
    const int rbase = 32 * w + 16 * hi;      // first of this thread's 16 rows

    const int2 cd   = chunk_desc[cid];
    const int rel   = cd.x;
    const int start = cd.y;
    const int e_cnt = min(CHUNK, offsets[rel + 1] - start);

    __shared__ float t_lds[CHUNK][DIM];
    __shared__ float h_lds[CHUNK][DIM];
    __shared__ float red[4][CHUNK];
    __shared__ float ht_red[CHUNK];
    __shared__ int   bidx[CHUNK];
    __shared__ float r2_red[4];

    const float* Rbase = rel_w + (size_t)rel * (DIM * DIM)
                               + (size_t)rbase * DIM + c4 * 4;

    // ---- stage t, h (16 threads per element, 2 float4 each) ----
    const int eg  = tid >> 4;
    const int sub = tid & 15;
    float4 t0 = make_float4(0.f,0.f,0.f,0.f), t1 = t0, g0 = t0, g1 = t0;
    int b = -1;
    if (eg < e_cnt) {
        b = bucket[start + eg];
        const float* tp = ent_w + (size_t)t_idx[b] * DIM + sub * 8;
        const float* hp = ent_w + (size_t)h_idx[b] * DIM + sub * 8;
        t0 = *(const float4*)tp;  t1 = *(const float4*)(tp + 4);
        g0 = *(const float4*)hp;  g1 = *(const float4*)(hp + 4);
    }
    *(float4*)&t_lds[eg][sub * 8]     = t0;
    *(float4*)&t_lds[eg][sub * 8 + 4] = t1;
    *(float4*)&h_lds[eg][sub * 8]     = g0;
    *(float4*)&h_lds[eg][sub * 8 + 4] = g1;

    float htp = dot4(t0,t0) + dot4(t1,t1) + dot4(g0,g0) + dot4(g1,g1);
    #pragma unroll
    for (int off = 8; off >= 1; off >>= 1) htp += __shfl_xor(htp, off);
    if (sub == 0) { ht_red[eg] = htp; bidx[eg] = b; }

    // ---- R half A (rows rbase..rbase+7) ----
    float4 rA[8];
    float r2 = 0.f;
    #pragma unroll
    for (int p = 0; p < 8; ++p) {
        rA[p] = *(const float4*)(Rbase + (size_t)p * DIM);
        r2 += dot4(rA[p], rA[p]);
    }

    __syncthreads();   // t/h staged

    float acc[CHUNK];
    #pragma unroll
    for (int e = 0; e < CHUNK; ++e) {
        const float4 t4 = *(const float4*)&t_lds[e][c4 * 4];
        const float4 h0 = *(const float4*)&h_lds[e][rbase];
        const float4 h1 = *(const float4*)&h_lds[e][rbase + 4];
        acc[e] = h0.x * dot4(rA[0], t4) + h0.y * dot4(rA[1], t4)
               + h0.z * dot4(rA[2], t4) + h0.w * dot4(rA[3], t4)
               + h1.x * dot4(rA[4], t4) + h1.y * dot4(rA[5], t4)
               + h1.z * dot4(rA[6], t4) + h1.w * dot4(rA[7], t4);
    }

    // ---- R half B (rows rbase+8..rbase+15), same registers ----
    #pragma unroll
    for (int p = 0; p < 8; ++p) {
        rA[p] = *(const float4*)(Rbase + (size_t)(8 + p) * DIM);
        r2 += dot4(rA[p], rA[p]);
    }
    #pragma unroll
    for (int e = 0; e < CHUNK; ++e) {
        const float4 t4 = *(const float4*)&t_lds[e][c4 * 4];
        const float4 h2 = *(const float4*)&h_lds[e][rbase + 8];
        const float4 h3 = *(const float4*)&h_lds[e][rbase + 12];
        acc[e] += h2.x * dot4(rA[0], t4) + h2.y * dot4(rA[1], t4)
                + h2.z * dot4(rA[2], t4) + h2.w * dot4(rA[3], t4)
                + h3.x * dot4(rA[4], t4) + h3.y * dot4(rA[5], t4)
                + h3.z * dot4(rA[6], t4) + h3.w * dot4(rA[7], t4);
    }

    // ---- reductions ----
    #pragma unroll
    for (int off = 32; off >= 1; off >>= 1) r2 += __shfl_xor(r2, off);
    if (l == 0) r2_red[w] = r2;

    #pragma unroll
    for (int e = 0; e < CHUNK; ++e) {
        float v = acc[e];
        #pragma unroll
        for (int off = 32; off >= 1; off >>= 1) v += __shfl_xor(v, off);
        if (l == 0) red[w][e] = v;
    }
    __syncthreads();

    if (tid == 0)
        chunk_r2[cid] = (float)e_cnt *
            (r2_red[0] + r2_red[1] + r2_red[2] + r2_red[3]);

    if (tid < e_cnt) {
        const float s  = red[0][tid] + red[1][tid] + red[2][tid] + red[3][tid];
        const int   bb = bidx[tid];
        scores_out[bb] = s;
        const float d  = s - labels[bb];
        partials[bb] = make_float2(d * d, ht_red[tid]);
    }
}

// ---------- final: fixed-order reduction -> loss ----------
__global__ void __launch_bounds__(512) final_kernel(
    const float2* __restrict__ partials,
    const float*  __restrict__ chunk_r2,
    const int*    __restrict__ n_chunks,
    float*        __restrict__ loss_out)
{
    const int tid = threadIdx.x;
    const int total = n_chunks[0];
    float err = 0.f, ht = 0.f, r2 = 0.f;
    for (int i = tid; i < BATCH; i += 512) {
        const float2 p = partials[i];
        err += p.x; ht += p.y;
    }
    for (int i = tid; i < total; i += 512) r2 += chunk_r2[i];

    __shared__ float re[8], rh[8], rr2[8];
    #pragma unroll
    for (int off = 32; off >= 1; off >>= 1) {
        err += __shfl_down(err, off);
        ht  += __shfl_down(ht, off);
        r2  += __shfl_down(r2, off);
    }
    if ((tid & 63) == 0) { const int v = tid >> 6; re[v] = err; rh[v] = ht; rr2[v] = r2; }
    __syncthreads();
    if (tid == 0) {
        err = 0.f; ht = 0.f; r2 = 0.f;
        for (int v = 0; v < 8; ++v) { err += re[v]; ht += rh[v]; r2 += rr2[v]; }
        const float mse   = err / (float)BATCH;
        const float norms = (ht / ((float)BATCH * DIM)
                           + r2 / ((float)BATCH * (float)(DIM * DIM))) / 3.0f;
        loss_out[0] = mse + ALPHA * norms;
    }
}

extern "C" void kernel_launch(void* const* d_in, const int* in_sizes, int n_in,
                              void* d_out, int out_size, void* d_ws, size_t ws_size,
                              hipStream_t stream) {
    const int*   h_idx  = (const int*)d_in[0];
    const int*   r_idx  = (const int*)d_in[1];
    const int*   t_idx  = (const int*)d_in[2];
    const float* labels = (const float*)d_in[3];
    const float* ent_w  = (const float*)d_in[4];
    const float* rel_w  = (const float*)d_in[5];

    float* out = (float*)d_out;   // [0]=loss, [1..BATCH]=scores

    // workspace layout (~215 KB)
    char* ws = (char*)d_ws;
    float2* partials   = (float2*)ws;           ws += BATCH * sizeof(float2);
    int*    bucket     = (int*)ws;              ws += BATCH * sizeof(int);
    int*    offsets    = (int*)ws;              ws += 512 * sizeof(int);
    int2*   chunk_desc = (int2*)ws;             ws += MAXCHUNKS * sizeof(int2);
    float*  chunk_r2   = (float*)ws;            ws += MAXCHUNKS * sizeof(float);
    int*    n_chunks   = (int*)ws;

    prep_kernel<<<1, 1024, 0, stream>>>(r_idx, offsets, bucket, chunk_desc, n_chunks);
    rescal_main_kernel<<<MAXCHUNKS, 256, 0, stream>>>(
        chunk_desc, n_chunks, offsets, bucket, h_idx, t_idx,
        labels, ent_w, rel_w, out + 1, partials, chunk_r2);
    final_kernel<<<1, 512, 0, stream>>>(partials, chunk_r2, n_chunks, out);
}

// Round 5
// 65.043 us; speedup vs baseline: 3.4536x; 3.4536x over previous
//
#include <hip/hip_runtime.h>

#define DIM       128
#define BATCH     16384
#define RELN      500
#define ALPHA     0.001f
#define CHUNK     8
#define MAXCHUNKS (BATCH / CHUNK + RELN)   // 2548 upper bound on total chunks

__device__ __forceinline__ float dot4(float4 a, float4 b) {
    return a.x * b.x + a.y * b.y + a.z * b.z + a.w * b.w;
}

// ---------- prep: ONE block does hist + scan + scatter + chunk list ----------
__global__ void __launch_bounds__(1024) prep_kernel(
    const int* __restrict__ r_idx,
    int*  __restrict__ offsets,      // [RELN+1]
    int*  __restrict__ bucket,       // [BATCH]
    int2* __restrict__ chunk_desc,   // [MAXCHUNKS] (rel, start)
    int*  __restrict__ n_chunks)
{
    __shared__ int cnt[512];
    __shared__ int offs[512];
    __shared__ int cur[512];
    const int tid = threadIdx.x;

    if (tid < 512) cnt[tid] = 0;
    __syncthreads();

    int myr[16];
    #pragma unroll
    for (int k = 0; k < 16; ++k) {
        myr[k] = r_idx[tid + k * 1024];
        atomicAdd(&cnt[myr[k]], 1);
    }
    __syncthreads();

    // inclusive scan of cnt -> offs
    if (tid < 512) offs[tid] = cnt[tid];
    __syncthreads();
    for (int d = 1; d < 512; d <<= 1) {
        int x = 0;
        if (tid < 512 && tid >= d) x = offs[tid - d];
        __syncthreads();
        if (tid < 512) offs[tid] += x;
        __syncthreads();
    }
    int excl = 0;
    if (tid < 512) {
        excl = offs[tid] - cnt[tid];
        cur[tid] = excl;
        if (tid < RELN) offsets[tid] = excl;
        if (tid == RELN - 1) offsets[RELN] = offs[tid];
    }
    __syncthreads();

    // scatter (order within a relation nondeterministic; no output depends on it)
    #pragma unroll
    for (int k = 0; k < 16; ++k) {
        const int pos = atomicAdd(&cur[myr[k]], 1);
        bucket[pos] = tid + k * 1024;
    }

    // chunk list: second scan over ceil(cnt/CHUNK)
    const int nc = (tid < RELN) ? (cnt[tid] + CHUNK - 1) / CHUNK : 0;
    __syncthreads();
    if (tid < 512) offs[tid] = nc;
    __syncthreads();
    for (int d = 1; d < 512; d <<= 1) {
        int x = 0;
        if (tid < 512 && tid >= d) x = offs[tid - d];
        __syncthreads();
        if (tid < 512) offs[tid] += x;
        __syncthreads();
    }
    if (tid == 511) n_chunks[0] = offs[511];
    if (tid < RELN) {
        const int cbase = offs[tid] - nc;
        for (int i = 0; i < nc; ++i)
            chunk_desc[cbase + i] = make_int2(tid, excl + i * CHUNK);
    }
}

// ---------- main: one block per chunk of 8; R in regs (two sequential halves) ----------
// Wave w, lane l: hi=l>>5, c4=l&31. Thread owns 16 CONSECUTIVE rows
// rbase=32w+16hi .. +15, float4 cols [4*c4, +4). R loaded as 8 float4 (half A,
// rows rbase..+7), consumed over all 8 elements, then half B reuses the SAME
// registers. Peak live ~60 VGPR; NO min-waves bound (hipcc under-allocates and
// spills/remats otherwise — R3/R4 counter evidence). h applied via 2-address
// broadcast LDS reads. Reduction trees slot-invariant -> deterministic.
__global__ void __launch_bounds__(256) rescal_main_kernel(
    const int2*  __restrict__ chunk_desc,
    const int*   __restrict__ n_chunks,
    const int*   __restrict__ offsets,
    const int*   __restrict__ bucket,
    const int*   __restrict__ h_idx,
    const int*   __restrict__ t_idx,
    const float* __restrict__ labels,
    const float* __restrict__ ent_w,
    const float* __restrict__ rel_w,
    float*       __restrict__ scores_out,   // d_out + 1
    float2*      __restrict__ partials,     // [BATCH] (err, h2+t2)
    float*       __restrict__ chunk_r2)     // [MAXCHUNKS] e_cnt * ||R||^2
{
    // bijective XCD swizzle: consecutive cids stay on one XCD -> R reuse in L2
    const int bid = blockIdx.x;
    const int xcd = bid & 7;
    const int j   = bid >> 3;
    const int q   = MAXCHUNKS / 8;
    const int r_  = MAXCHUNKS % 8;
    const int cid = (xcd < r_ ? xcd * (q + 1) : r_ * (q + 1) + (xcd - r_) * q) + j;

    const int total = n_chunks[0];
    if (cid >= total) return;

    const int tid = threadIdx.x;
    const int w   = tid >> 6;
    const int l   = tid & 63;
    const int hi  = l >> 5;
    const int c4  = l & 31;
    const int rbase = 32 * w + 16 * hi;      // first of this thread's 16 rows

    const int2 cd   = chunk_desc[cid];
    const int rel   = cd.x;
    const int start = cd.y;
    const int e_cnt = min(CHUNK, offsets[rel + 1] - start);

    __shared__ float t_lds[CHUNK][DIM];
    __shared__ float h_lds[CHUNK][DIM];
    __shared__ float red[4][CHUNK];
    __shared__ float ht_red[CHUNK];
    __shared__ int   bidx[CHUNK];
    __shared__ float r2_red[4];

    const float* Rbase = rel_w + (size_t)rel * (DIM * DIM)
                               + (size_t)rbase * DIM + c4 * 4;

    // ---- stage t, h (32 threads per element, 1 float4 each) ----
    const int eg   = tid >> 5;      // element slot 0..7
    const int col4 = tid & 31;
    float4 tv4 = make_float4(0.f, 0.f, 0.f, 0.f);
    float4 hv4 = tv4;
    int b = -1;
    if (eg < e_cnt) {
        b   = bucket[start + eg];
        tv4 = *(const float4*)(ent_w + (size_t)t_idx[b] * DIM + col4 * 4);
        hv4 = *(const float4*)(ent_w + (size_t)h_idx[b] * DIM + col4 * 4);
    }
    *(float4*)&t_lds[eg][col4 * 4] = tv4;
    *(float4*)&h_lds[eg][col4 * 4] = hv4;

    float htp = dot4(tv4, tv4) + dot4(hv4, hv4);
    #pragma unroll
    for (int off = 16; off >= 1; off >>= 1) htp += __shfl_xor(htp, off);
    if ((tid & 31) == 0) { ht_red[eg] = htp; bidx[eg] = b; }

    // ---- R half A (rows rbase..rbase+7) ----
    float4 rA[8];
    float r2 = 0.f;
    #pragma unroll
    for (int p = 0; p < 8; ++p) {
        rA[p] = *(const float4*)(Rbase + (size_t)p * DIM);
        r2 += dot4(rA[p], rA[p]);
    }

    __syncthreads();   // t/h staged

    float acc[CHUNK];
    #pragma unroll
    for (int e = 0; e < CHUNK; ++e) {
        const float4 t4 = *(const float4*)&t_lds[e][c4 * 4];
        const float4 h0 = *(const float4*)&h_lds[e][rbase];
        const float4 h1 = *(const float4*)&h_lds[e][rbase + 4];
        acc[e] = h0.x * dot4(rA[0], t4) + h0.y * dot4(rA[1], t4)
               + h0.z * dot4(rA[2], t4) + h0.w * dot4(rA[3], t4)
               + h1.x * dot4(rA[4], t4) + h1.y * dot4(rA[5], t4)
               + h1.z * dot4(rA[6], t4) + h1.w * dot4(rA[7], t4);
    }

    // ---- R half B (rows rbase+8..rbase+15), same registers ----
    #pragma unroll
    for (int p = 0; p < 8; ++p) {
        rA[p] = *(const float4*)(Rbase + (size_t)(8 + p) * DIM);
        r2 += dot4(rA[p], rA[p]);
    }
    #pragma unroll
    for (int e = 0; e < CHUNK; ++e) {
        const float4 t4 = *(const float4*)&t_lds[e][c4 * 4];
        const float4 h2 = *(const float4*)&h_lds[e][rbase + 8];
        const float4 h3 = *(const float4*)&h_lds[e][rbase + 12];
        acc[e] += h2.x * dot4(rA[0], t4) + h2.y * dot4(rA[1], t4)
                + h2.z * dot4(rA[2], t4) + h2.w * dot4(rA[3], t4)
                + h3.x * dot4(rA[4], t4) + h3.y * dot4(rA[5], t4)
                + h3.z * dot4(rA[6], t4) + h3.w * dot4(rA[7], t4);
    }

    // ---- reductions ----
    #pragma unroll
    for (int off = 32; off >= 1; off >>= 1) r2 += __shfl_xor(r2, off);
    if (l == 0) r2_red[w] = r2;

    #pragma unroll
    for (int e = 0; e < CHUNK; ++e) {
        float v = acc[e];
        #pragma unroll
        for (int off = 32; off >= 1; off >>= 1) v += __shfl_xor(v, off);
        if (l == 0) red[w][e] = v;
    }
    __syncthreads();

    if (tid == 0)
        chunk_r2[cid] = (float)e_cnt *
            (r2_red[0] + r2_red[1] + r2_red[2] + r2_red[3]);

    if (tid < e_cnt) {
        const float s  = red[0][tid] + red[1][tid] + red[2][tid] + red[3][tid];
        const int   bb = bidx[tid];
        scores_out[bb] = s;
        const float d  = s - labels[bb];
        partials[bb] = make_float2(d * d, ht_red[tid]);
    }
}

// ---------- final: fixed-order reduction -> loss ----------
__global__ void __launch_bounds__(512) final_kernel(
    const float2* __restrict__ partials,
    const float*  __restrict__ chunk_r2,
    const int*    __restrict__ n_chunks,
    float*        __restrict__ loss_out)
{
    const int tid = threadIdx.x;
    const int total = n_chunks[0];
    float err = 0.f, ht = 0.f, r2 = 0.f;
    for (int i = tid; i < BATCH; i += 512) {
        const float2 p = partials[i];
        err += p.x; ht += p.y;
    }
    for (int i = tid; i < total; i += 512) r2 += chunk_r2[i];

    __shared__ float re[8], rh[8], rr2[8];
    #pragma unroll
    for (int off = 32; off >= 1; off >>= 1) {
        err += __shfl_down(err, off);
        ht  += __shfl_down(ht, off);
        r2  += __shfl_down(r2, off);
    }
    if ((tid & 63) == 0) { const int v = tid >> 6; re[v] = err; rh[v] = ht; rr2[v] = r2; }
    __syncthreads();
    if (tid == 0) {
        err = 0.f; ht = 0.f; r2 = 0.f;
        for (int v = 0; v < 8; ++v) { err += re[v]; ht += rh[v]; r2 += rr2[v]; }
        const float mse   = err / (float)BATCH;
        const float norms = (ht / ((float)BATCH * DIM)
                           + r2 / ((float)BATCH * (float)(DIM * DIM))) / 3.0f;
        loss_out[0] = mse + ALPHA * norms;
    }
}

extern "C" void kernel_launch(void* const* d_in, const int* in_sizes, int n_in,
                              void* d_out, int out_size, void* d_ws, size_t ws_size,
                              hipStream_t stream) {
    const int*   h_idx  = (const int*)d_in[0];
    const int*   r_idx  = (const int*)d_in[1];
    const int*   t_idx  = (const int*)d_in[2];
    const float* labels = (const float*)d_in[3];
    const float* ent_w  = (const float*)d_in[4];
    const float* rel_w  = (const float*)d_in[5];

    float* out = (float*)d_out;   // [0]=loss, [1..BATCH]=scores

    // workspace layout (~225 KB)
    char* ws = (char*)d_ws;
    float2* partials   = (float2*)ws;           ws += BATCH * sizeof(float2);
    int*    bucket     = (int*)ws;              ws += BATCH * sizeof(int);
    int*    offsets    = (int*)ws;              ws += 512 * sizeof(int);
    int2*   chunk_desc = (int2*)ws;             ws += MAXCHUNKS * sizeof(int2);
    float*  chunk_r2   = (float*)ws;            ws += MAXCHUNKS * sizeof(float);
    int*    n_chunks   = (int*)ws;

    prep_kernel<<<1, 1024, 0, stream>>>(r_idx, offsets, bucket, chunk_desc, n_chunks);
    rescal_main_kernel<<<MAXCHUNKS, 256, 0, stream>>>(
        chunk_desc, n_chunks, offsets, bucket, h_idx, t_idx,
        labels, ent_w, rel_w, out + 1, partials, chunk_r2);
    final_kernel<<<1, 512, 0, stream>>>(partials, chunk_r2, n_chunks, out);
}